// Round 2
// baseline (359.893 us; speedup 1.0000x reference)
//
#include <hip/hip_runtime.h>
#include <math.h>

// Problem constants (from reference)
#define BATCH 262144
#define DIM   128
#define NCLS  40
#define NCP   48             // classes padded to 3 MFMA tiles of 16
#define CD    (NCLS * DIM)   // 5120
// LAMBDA_R=1.0, LAMBDA_C=0.5, LAMBDA_M=1.0, MOMENTUM=0.1

#define TB1 512            // k1: 8 waves/block
#define NB1 256            // k1 blocks: 1024 rows/block (5.24 MB partials --
                           // round-0-proven workspace footprint)
#define TB3 256            // k3: 4 waves/block, 64 rows/wave
#define NB3 (BATCH / 256)  // 1024 blocks

typedef __attribute__((ext_vector_type(8))) short short8;  // 8 bf16 = 4 VGPRs
typedef __attribute__((ext_vector_type(4))) float f32x4;   // MFMA C/D

// fp32 -> bf16 round-to-nearest-even (bit trick; inputs are finite)
__device__ __forceinline__ short f2bf(float f) {
    unsigned u = __float_as_uint(f);
    u += 0x7fffu + ((u >> 16) & 1u);
    return (short)(u >> 16);
}

// ---------------------------------------------------------------------------
// K1: segmented sum.
// ds_add_f32 (atomicAdd on LDS, fire-and-forget) instead of read-modify-write
// — kills the dependent ds_read->add->ds_write chain (cls unknown => compiler
// had to serialize on may-alias). Accumulators shared by wave pairs
// (p,p^1 at same h) — safe under atomics — so LDS drops 82->41 KB and
// occupancy doubles to 2 blocks/CU (4 waves/SIMD).
// part_sums stays at the round-0 size (NB1=256): workspace-safe.
// ---------------------------------------------------------------------------
__global__ __launch_bounds__(TB1) void k1_segsum(const float* __restrict__ z,
                                                 const int* __restrict__ y,
                                                 float* __restrict__ part_sums,
                                                 float* __restrict__ gcnt) {
    __shared__ float s_acc[4][NCLS * 64];   // 40960 B
    __shared__ float s_cnt[NCLS];
    const int t = threadIdx.x;
    for (int i = t; i < 4 * NCLS * 64; i += TB1) ((float*)s_acc)[i] = 0.0f;
    if (t < NCLS) s_cnt[t] = 0.0f;
    __syncthreads();

    const int w    = t >> 6;        // wave 0..7
    const int lane = t & 63;
    const int p    = w >> 1;        // row phase 0..3
    const int h    = w & 1;         // dim half 0/1
    const int base = blockIdx.x * 1024;
    // waves (p,h) and (p^1,h) share one accumulator (same dims, disjoint rows)
    float* __restrict__ acc = s_acc[(p >> 1) * 2 + h];

    int yy[4];
#pragma unroll
    for (int g = 0; g < 4; ++g) yy[g] = y[base + 4 * (g * 64 + lane) + p];

    if (h == 0) {
#pragma unroll
        for (int g = 0; g < 4; ++g) atomicAdd(&s_cnt[yy[g]], 1.0f);
    }

    const float* __restrict__ zp = z + (size_t)base * DIM + h * 64 + lane;

    float vb[8];
#pragma unroll
    for (int q = 0; q < 8; ++q) vb[q] = zp[(size_t)(4 * q + p) * DIM];

#pragma unroll 1
    for (int g = 0; g < 4; ++g) {
        const int yg = yy[g];
#pragma unroll
        for (int j0 = 0; j0 < 64; j0 += 8) {
#pragma unroll
            for (int q = 0; q < 8; ++q) {
                const int sj = g * 64 + j0 + q;
                const float v = vb[q];
                int sn = sj + 8;
                if (sn > 255) sn = sj;
                vb[q] = zp[(size_t)(4 * sn + p) * DIM];
                const int cls = __builtin_amdgcn_readlane(yg, j0 + q);
                atomicAdd(&acc[cls * 64 + lane], v);   // ds_add_f32, no return
            }
        }
    }
    __syncthreads();

    float* __restrict__ ps = part_sums + (size_t)blockIdx.x * CD;
    for (int i = t; i < CD; i += TB1) {
        const int cls = i >> 7;
        const int d   = i & 127;
        const int hh  = d >> 6, dl = d & 63;
        ps[i] = s_acc[hh][cls * 64 + dl] + s_acc[2 + hh][cls * 64 + dl];
    }
    if (t < NCLS) atomicAdd(&gcnt[t], s_cnt[t]);
}

// ---------------------------------------------------------------------------
// K2: reduce partials -> EMA centers; emit bf16 c [48][128] + fp32 c2 [48].
// 512 threads/block, 4-way split of the NB1-deep reduction (64 serial
// strided loads/thread instead of 256 — latency-bound kernel).
// Pad classes 40..47: c=0, c2=1e30 (excluded from min; dot(z,0)=0).
// ---------------------------------------------------------------------------
__global__ __launch_bounds__(512) void k2_centers(const float* __restrict__ part_sums,
                                                  const float* __restrict__ gcnt,
                                                  const float* __restrict__ centers,
                                                  short* __restrict__ cbf,
                                                  float* __restrict__ c2_out) {
    const int j  = blockIdx.x;    // class (0..47)
    const int t  = threadIdx.x;
    const int d  = t & 127;       // dim
    const int qr = t >> 7;        // quarter 0..3

    if (j >= NCLS) {
        if (qr == 0) cbf[j * DIM + d] = 0;
        if (t == 0) c2_out[j] = 1e30f;
        return;                    // whole block exits before any barrier
    }

    const float* __restrict__ p = part_sums + j * DIM + d + (size_t)(qr * 64) * CD;
    float s = 0.0f;
#pragma unroll 8
    for (int b = 0; b < 64; ++b) s += p[(size_t)b * CD];

    __shared__ float red[512];
    red[t] = s;
    __syncthreads();

    float cv = 0.0f;
    if (qr == 0) {
        const float ssum = red[d] + red[d + 128] + red[d + 256] + red[d + 384];
        const float cnt  = gcnt[j];
        const float mean = ssum / fmaxf(cnt, 1.0f);
        const float ctr  = centers[j * DIM + d];
        const float ema  = 0.9f * ctr + 0.1f * mean;
        cv = (cnt > 0.0f) ? ema : ctr;
        cbf[j * DIM + d] = f2bf(cv);
    }
    __syncthreads();
    red[t] = cv * cv;    // qr!=0 contributes 0
    __syncthreads();
    for (int off = 256; off > 0; off >>= 1) {
        if (t < off) red[t] += red[t + off];
        __syncthreads();
    }
    if (t == 0) c2_out[j] = red[0];
}

// ---------------------------------------------------------------------------
// K3: MFMA Gram kernel. Per wave: 64 rows x 48 classes via 16x16x32 bf16
// MFMA (4 row-subtiles x 3 class-subtiles x 4 K-steps = 48 MFMA).
//  * z2 stored in the unused col 48 of each stride-52 s_S row; s_red aliased
//    onto s_S after a barrier. LDS 55,488 -> 53,440 B => 3 blocks/CU
//    (12 waves/CU, was 2 blocks/8 waves). __launch_bounds__(256,3) pins it.
//  * k4 folded in: one global atomicAdd of the block partial (out pre-zeroed).
// D layout: col=lane&15 (class), row=(lane>>4)*4+reg  [m89-verified].
// ---------------------------------------------------------------------------
__global__ __launch_bounds__(TB3, 3) void k3_loss(const float* __restrict__ z,
                                                  const int* __restrict__ y,
                                                  const short* __restrict__ cbf,
                                                  const float* __restrict__ c2,
                                                  const float* __restrict__ tr,
                                                  const float* __restrict__ mg,
                                                  float* __restrict__ out) {
    __shared__ float s_S[4][64 * 52];   // 53248 B; col 48 of each row = z2
    __shared__ float s_c2[NCP];         // 192 B

    const int t = threadIdx.x;
    if (t < NCP) s_c2[t] = c2[t];

    const int w    = t >> 6;
    const int lane = t & 63;
    const int q    = lane >> 4;     // k-quad 0..3
    const int col  = lane & 15;
    const int wavebase = blockIdx.x * 256 + w * 64;

    // B fragments, preloaded once: 12 x short8 (48 VGPRs)
    short8 bfrag[3][4];
#pragma unroll
    for (int ct = 0; ct < 3; ++ct)
#pragma unroll
        for (int s = 0; s < 4; ++s)
            bfrag[ct][s] = *(const short8*)(cbf + (ct * 16 + col) * DIM + s * 32 + q * 8);

    __syncthreads();   // s_c2 visible to all waves

#pragma unroll 1
    for (int rt = 0; rt < 4; ++rt) {
        const float* __restrict__ zrow =
            z + (size_t)(wavebase + rt * 16 + col) * DIM + q * 8;

        float4 f[8];
#pragma unroll
        for (int s = 0; s < 4; ++s) {
            f[2 * s]     = *(const float4*)(zrow + s * 32);
            f[2 * s + 1] = *(const float4*)(zrow + s * 32 + 4);
        }

        // exact fp32 partial ||z||^2 over my 32 dims
        float zp = 0.0f;
#pragma unroll
        for (int i = 0; i < 8; ++i) {
            zp = fmaf(f[i].x, f[i].x, zp);
            zp = fmaf(f[i].y, f[i].y, zp);
            zp = fmaf(f[i].z, f[i].z, zp);
            zp = fmaf(f[i].w, f[i].w, zp);
        }

        // convert to bf16 A-fragments
        short8 afr[4];
#pragma unroll
        for (int s = 0; s < 4; ++s) {
            const float4 f0 = f[2 * s], f1 = f[2 * s + 1];
            afr[s][0] = f2bf(f0.x); afr[s][1] = f2bf(f0.y);
            afr[s][2] = f2bf(f0.z); afr[s][3] = f2bf(f0.w);
            afr[s][4] = f2bf(f1.x); afr[s][5] = f2bf(f1.y);
            afr[s][6] = f2bf(f1.z); afr[s][7] = f2bf(f1.w);
        }

        f32x4 acc0 = {0.f, 0.f, 0.f, 0.f};
        f32x4 acc1 = {0.f, 0.f, 0.f, 0.f};
        f32x4 acc2 = {0.f, 0.f, 0.f, 0.f};
#pragma unroll
        for (int s = 0; s < 4; ++s) {
            acc0 = __builtin_amdgcn_mfma_f32_16x16x32_bf16(afr[s], bfrag[0][s], acc0, 0, 0, 0);
            acc1 = __builtin_amdgcn_mfma_f32_16x16x32_bf16(afr[s], bfrag[1][s], acc1, 0, 0, 0);
            acc2 = __builtin_amdgcn_mfma_f32_16x16x32_bf16(afr[s], bfrag[2][s], acc2, 0, 0, 0);
        }

        // z2: reduce the 4 k-quads (lanes xor 16, 32); park in col 48
        zp += __shfl_xor(zp, 16);
        zp += __shfl_xor(zp, 32);
        if (q == 0) s_S[w][(rt * 16 + col) * 52 + 48] = zp;

        // dump S tile: row = rt*16 + q*4 + reg, class = ct*16 + col
#pragma unroll
        for (int reg = 0; reg < 4; ++reg) {
            const int rr = rt * 16 + q * 4 + reg;
            s_S[w][rr * 52 + col]      = acc0[reg];
            s_S[w][rr * 52 + 16 + col] = acc1[reg];
            s_S[w][rr * 52 + 32 + col] = acc2[reg];
        }
    }
    // s_S rows are per-wave private; in-order DS pipe makes them visible
    // to this wave without a barrier.

    // ---- scalar epilogue: 1 thread = 1 row ----
    const int row = blockIdx.x * 256 + t;
    const int cls = y[row];
    const float z2v = s_S[w][lane * 52 + 48];

    float own_d2 = 0.0f;
    float mind2  = 3.4e38f;
#pragma unroll
    for (int k = 0; k < 12; ++k) {
        const float4 Sv = *(const float4*)&s_S[w][lane * 52 + 4 * k];
        const float Se[4] = {Sv.x, Sv.y, Sv.z, Sv.w};
#pragma unroll
        for (int e = 0; e < 4; ++e) {
            const int j = 4 * k + e;
            float d2 = fmaxf(z2v + s_c2[j] - 2.0f * Se[e], 0.0f);
            const bool isown = (j == cls);
            own_d2 = isown ? d2 : own_d2;
            mind2  = isown ? mind2 : fminf(mind2, d2);
        }
    }

    const float r  = sqrtf(z2v);
    const float dd = r - tr[cls];
    const float ad = fabsf(dd);
    const float rad = (ad < 1.0f) ? 0.5f * dd * dd : ad - 0.5f;

    const float dist = sqrtf(mind2);
    const float marg = fmaxf(mg[cls] - dist, 0.0f);

    const float tot = rad + 0.5f * own_d2 + marg;

    // block reduce: alias s_red onto s_S (all s_S reads done after barrier)
    __syncthreads();
    float* s_red = &s_S[0][0];
    s_red[t] = tot;
    __syncthreads();
    for (int off = TB3 / 2; off > 0; off >>= 1) {
        if (t < off) s_red[t] += s_red[t + off];
        __syncthreads();
    }
    if (t == 0) atomicAdd(out, s_red[0] * (1.0f / (float)BATCH));
}

// ---------------------------------------------------------------------------
extern "C" void kernel_launch(void* const* d_in, const int* in_sizes, int n_in,
                              void* d_out, int out_size, void* d_ws, size_t ws_size,
                              hipStream_t stream) {
    const float* z       = (const float*)d_in[0];  // [BATCH, DIM] fp32
    const int*   y       = (const int*)d_in[1];    // [BATCH] int32
    const float* centers = (const float*)d_in[2];  // [NCLS, DIM] fp32
    // d_in[3] = initialized (all True, unused — see K2 note)
    const float* tr      = (const float*)d_in[4];  // [NCLS] target_radii
    const float* mg      = (const float*)d_in[5];  // [NCLS] margins
    float* out = (float*)d_out;

    float* ws        = (float*)d_ws;
    float* part_sums = ws;                                   // NB1*CD (5.24 MB)
    float* c2buf     = part_sums + (size_t)NB1 * CD;         // NCP
    float* gcnt      = c2buf + NCP;                          // NCLS
    short* cbf       = (short*)(gcnt + NCLS);                // NCP*DIM bf16

    hipMemsetAsync(gcnt, 0, NCLS * sizeof(float), stream);
    hipMemsetAsync(out, 0, sizeof(float), stream);

    k1_segsum<<<NB1, TB1, 0, stream>>>(z, y, part_sums, gcnt);
    k2_centers<<<NCP, 512, 0, stream>>>(part_sums, gcnt, centers, cbf, c2buf);
    k3_loss<<<NB3, TB3, 0, stream>>>(z, y, cbf, c2buf, tr, mg, out);
}

// Round 4
// 264.832 us; speedup vs baseline: 1.3589x; 1.3589x over previous
//
#include <hip/hip_runtime.h>
#include <math.h>

// Problem constants (from reference)
#define BATCH 262144
#define DIM   128
#define NCLS  40
#define NCP   48             // classes padded to 3 MFMA tiles of 16
#define CD    (NCLS * DIM)   // 5120
// LAMBDA_R=1.0, LAMBDA_C=0.5, LAMBDA_M=1.0, MOMENTUM=0.1

#define TB1 512            // k1: 8 waves/block
#define NB1 256            // k1 blocks: 1024 rows/block (5.24 MB partials)
#define TB3 256            // k3: 4 waves/block, 64 rows/wave
#define NB3 (BATCH / 256)  // 1024 blocks

typedef __attribute__((ext_vector_type(8))) short short8;  // 8 bf16 = 4 VGPRs
typedef __attribute__((ext_vector_type(4))) float f32x4;   // MFMA C/D

// fp32 -> bf16 round-to-nearest-even (bit trick; inputs are finite)
__device__ __forceinline__ short f2bf(float f) {
    unsigned u = __float_as_uint(f);
    u += 0x7fffu + ((u >> 16) & 1u);
    return (short)(u >> 16);
}

// 40-way static accumulator machinery: class index is wave-uniform per row
// (readlane), so a switch selects one of 40 NAMED VGPRs — no LDS RMW chain,
// no runtime-indexed array (rule #20: that would go to scratch).
#define K1_ALL(M) M(0) M(1) M(2) M(3) M(4) M(5) M(6) M(7) M(8) M(9) \
                  M(10) M(11) M(12) M(13) M(14) M(15) M(16) M(17) M(18) M(19) \
                  M(20) M(21) M(22) M(23) M(24) M(25) M(26) M(27) M(28) M(29) \
                  M(30) M(31) M(32) M(33) M(34) M(35) M(36) M(37) M(38) M(39)
#define K1_DECL(c) float a##c = 0.0f;
#define K1_CASE(c) case c: a##c += v; break;
#define K1_ST(c)   s_acc[w][(c) * 64 + lane] = a##c;

// ---------------------------------------------------------------------------
// K1: segmented sum. Global-load ring is round-0 VERBATIM (proven <76us).
// Accumulation moved from LDS RMW (serialized ~120cyc ds round-trip per row:
// compiler can't reorder ds_read[i+1] before ds_write[i] on runtime cls) to
// 40 named VGPRs selected by a switch on the wave-uniform class. The j0 loop
// is NOT unrolled so the code holds only 8 switch instances (I-cache safe).
// LDS touched once at the end: plain per-wave stores + round-0 combine/write.
// ---------------------------------------------------------------------------
__global__ __launch_bounds__(TB1) void k1_segsum(const float* __restrict__ z,
                                                 const int* __restrict__ y,
                                                 float* __restrict__ ps,
                                                 float* __restrict__ gcnt) {
    __shared__ float s_acc[8][NCLS * 64];   // 81920 B (write-once, no RMW)
    __shared__ float s_cnt[NCLS];
    const int t = threadIdx.x;
    if (t < NCLS) s_cnt[t] = 0.0f;
    __syncthreads();

    const int w    = t >> 6;        // wave 0..7
    const int lane = t & 63;
    const int p    = w >> 1;        // row phase 0..3
    const int h    = w & 1;         // dim half 0/1
    const int base = blockIdx.x * 1024;

    int yy[4];
#pragma unroll
    for (int g = 0; g < 4; ++g) yy[g] = y[base + 4 * (g * 64 + lane) + p];

    if (h == 0) {
#pragma unroll
        for (int g = 0; g < 4; ++g) atomicAdd(&s_cnt[yy[g]], 1.0f);
    }

    const float* __restrict__ zp = z + (size_t)base * DIM + h * 64 + lane;

    float vb[8];
#pragma unroll
    for (int q = 0; q < 8; ++q) vb[q] = zp[(size_t)(4 * q + p) * DIM];

    K1_ALL(K1_DECL)                 // 40 fp32 accumulators in VGPRs

#pragma unroll 1
    for (int g = 0; g < 4; ++g) {
        const int yg = yy[g];
#pragma unroll 1
        for (int j0 = 0; j0 < 64; j0 += 8) {
#pragma unroll
            for (int q = 0; q < 8; ++q) {
                const int sj = g * 64 + j0 + q;
                const float v = vb[q];
                int sn = sj + 8;
                if (sn > 255) sn = sj;
                vb[q] = zp[(size_t)(4 * sn + p) * DIM];
                const int cls = __builtin_amdgcn_readlane(yg, j0 + q);
                switch (cls) { K1_ALL(K1_CASE) default: break; }
            }
        }
    }

    // dump the 40 accumulators (plain stores, independent)
    K1_ALL(K1_ST)
    __syncthreads();

    // round-0 combine/write: 4 row-phases summed per (class, dim)
    float* __restrict__ ps_b = ps + (size_t)blockIdx.x * CD;
    for (int i = t; i < CD; i += TB1) {
        const int cls = i >> 7;
        const int d   = i & 127;
        const int hh  = d >> 6, dl = d & 63;
        float ssum = 0.0f;
#pragma unroll
        for (int pp = 0; pp < 4; ++pp) ssum += s_acc[(pp << 1) | hh][cls * 64 + dl];
        ps_b[i] = ssum;
    }
    if (t < NCLS) atomicAdd(&gcnt[t], s_cnt[t]);
}

// ---------------------------------------------------------------------------
// K2: reduce partials -> EMA centers; emit bf16 c [48][128] + fp32 c2 [48].
// Round-2-proven: 512 threads/block, 4-way split of the 256-deep reduction.
// Pad classes 40..47: c=0, c2=1e30 (excluded from min; dot(z,0)=0).
// ---------------------------------------------------------------------------
__global__ __launch_bounds__(512) void k2_centers(const float* __restrict__ part_sums,
                                                  const float* __restrict__ gcnt,
                                                  const float* __restrict__ centers,
                                                  short* __restrict__ cbf,
                                                  float* __restrict__ c2_out) {
    const int j  = blockIdx.x;    // class (0..47)
    const int t  = threadIdx.x;
    const int d  = t & 127;       // dim
    const int qr = t >> 7;        // quarter 0..3

    if (j >= NCLS) {
        if (qr == 0) cbf[j * DIM + d] = 0;
        if (t == 0) c2_out[j] = 1e30f;
        return;                    // whole block exits before any barrier
    }

    const float* __restrict__ p = part_sums + j * DIM + d + (size_t)(qr * 64) * CD;
    float s = 0.0f;
#pragma unroll 8
    for (int b = 0; b < 64; ++b) s += p[(size_t)b * CD];

    __shared__ float red[512];
    red[t] = s;
    __syncthreads();

    float cv = 0.0f;
    if (qr == 0) {
        const float ssum = red[d] + red[d + 128] + red[d + 256] + red[d + 384];
        const float cnt  = gcnt[j];
        const float mean = ssum / fmaxf(cnt, 1.0f);
        const float ctr  = centers[j * DIM + d];
        const float ema  = 0.9f * ctr + 0.1f * mean;
        cv = (cnt > 0.0f) ? ema : ctr;
        cbf[j * DIM + d] = f2bf(cv);
    }
    __syncthreads();
    red[t] = cv * cv;    // qr!=0 contributes 0
    __syncthreads();
    for (int off = 256; off > 0; off >>= 1) {
        if (t < off) red[t] += red[t + off];
        __syncthreads();
    }
    if (t == 0) c2_out[j] = red[0];
}

// ---------------------------------------------------------------------------
// K3: MFMA Gram kernel. Per wave: 64 rows x 48 classes via 16x16x32 bf16
// MFMA (4 row-subtiles x 3 class-subtiles x 4 K-steps = 48 MFMA).
//  * z2 in unused col 48 of the stride-52 s_S rows; s_red aliased onto s_S.
//    LDS 53.2 KB permits 3 blocks/CU naturally; NO min-waves pin (avoid
//    forcing spills — let the allocator choose).
//  * k4 fused: one global atomicAdd of the block partial (out pre-zeroed) —
//    round-2-proven.
// D layout: col=lane&15 (class), row=(lane>>4)*4+reg  [m89-verified].
// ---------------------------------------------------------------------------
__global__ __launch_bounds__(TB3) void k3_loss(const float* __restrict__ z,
                                               const int* __restrict__ y,
                                               const short* __restrict__ cbf,
                                               const float* __restrict__ c2,
                                               const float* __restrict__ tr,
                                               const float* __restrict__ mg,
                                               float* __restrict__ out) {
    __shared__ float s_S[4][64 * 52];   // 53248 B; col 48 of each row = z2
    __shared__ float s_c2[NCP];         // 192 B

    const int t = threadIdx.x;
    if (t < NCP) s_c2[t] = c2[t];

    const int w    = t >> 6;
    const int lane = t & 63;
    const int q    = lane >> 4;     // k-quad 0..3
    const int col  = lane & 15;
    const int wavebase = blockIdx.x * 256 + w * 64;

    // B fragments, preloaded once: 12 x short8 (48 VGPRs)
    short8 bfrag[3][4];
#pragma unroll
    for (int ct = 0; ct < 3; ++ct)
#pragma unroll
        for (int s = 0; s < 4; ++s)
            bfrag[ct][s] = *(const short8*)(cbf + (ct * 16 + col) * DIM + s * 32 + q * 8);

    __syncthreads();   // s_c2 visible to all waves

#pragma unroll 1
    for (int rt = 0; rt < 4; ++rt) {
        const float* __restrict__ zrow =
            z + (size_t)(wavebase + rt * 16 + col) * DIM + q * 8;

        float4 f[8];
#pragma unroll
        for (int s = 0; s < 4; ++s) {
            f[2 * s]     = *(const float4*)(zrow + s * 32);
            f[2 * s + 1] = *(const float4*)(zrow + s * 32 + 4);
        }

        // exact fp32 partial ||z||^2 over my 32 dims
        float zp = 0.0f;
#pragma unroll
        for (int i = 0; i < 8; ++i) {
            zp = fmaf(f[i].x, f[i].x, zp);
            zp = fmaf(f[i].y, f[i].y, zp);
            zp = fmaf(f[i].z, f[i].z, zp);
            zp = fmaf(f[i].w, f[i].w, zp);
        }

        // convert to bf16 A-fragments
        short8 afr[4];
#pragma unroll
        for (int s = 0; s < 4; ++s) {
            const float4 f0 = f[2 * s], f1 = f[2 * s + 1];
            afr[s][0] = f2bf(f0.x); afr[s][1] = f2bf(f0.y);
            afr[s][2] = f2bf(f0.z); afr[s][3] = f2bf(f0.w);
            afr[s][4] = f2bf(f1.x); afr[s][5] = f2bf(f1.y);
            afr[s][6] = f2bf(f1.z); afr[s][7] = f2bf(f1.w);
        }

        f32x4 acc0 = {0.f, 0.f, 0.f, 0.f};
        f32x4 acc1 = {0.f, 0.f, 0.f, 0.f};
        f32x4 acc2 = {0.f, 0.f, 0.f, 0.f};
#pragma unroll
        for (int s = 0; s < 4; ++s) {
            acc0 = __builtin_amdgcn_mfma_f32_16x16x32_bf16(afr[s], bfrag[0][s], acc0, 0, 0, 0);
            acc1 = __builtin_amdgcn_mfma_f32_16x16x32_bf16(afr[s], bfrag[1][s], acc1, 0, 0, 0);
            acc2 = __builtin_amdgcn_mfma_f32_16x16x32_bf16(afr[s], bfrag[2][s], acc2, 0, 0, 0);
        }

        // z2: reduce the 4 k-quads (lanes xor 16, 32); park in col 48
        zp += __shfl_xor(zp, 16);
        zp += __shfl_xor(zp, 32);
        if (q == 0) s_S[w][(rt * 16 + col) * 52 + 48] = zp;

        // dump S tile: row = rt*16 + q*4 + reg, class = ct*16 + col
#pragma unroll
        for (int reg = 0; reg < 4; ++reg) {
            const int rr = rt * 16 + q * 4 + reg;
            s_S[w][rr * 52 + col]      = acc0[reg];
            s_S[w][rr * 52 + 16 + col] = acc1[reg];
            s_S[w][rr * 52 + 32 + col] = acc2[reg];
        }
    }
    // s_S rows are per-wave private; in-order DS pipe makes them visible
    // to this wave without a barrier.

    // ---- scalar epilogue: 1 thread = 1 row ----
    const int row = blockIdx.x * 256 + t;
    const int cls = y[row];
    const float z2v = s_S[w][lane * 52 + 48];

    float own_d2 = 0.0f;
    float mind2  = 3.4e38f;
#pragma unroll
    for (int k = 0; k < 12; ++k) {
        const float4 Sv = *(const float4*)&s_S[w][lane * 52 + 4 * k];
        const float Se[4] = {Sv.x, Sv.y, Sv.z, Sv.w};
#pragma unroll
        for (int e = 0; e < 4; ++e) {
            const int j = 4 * k + e;
            float d2 = fmaxf(z2v + s_c2[j] - 2.0f * Se[e], 0.0f);
            const bool isown = (j == cls);
            own_d2 = isown ? d2 : own_d2;
            mind2  = isown ? mind2 : fminf(mind2, d2);
        }
    }

    const float r  = sqrtf(z2v);
    const float dd = r - tr[cls];
    const float ad = fabsf(dd);
    const float rad = (ad < 1.0f) ? 0.5f * dd * dd : ad - 0.5f;

    const float dist = sqrtf(mind2);
    const float marg = fmaxf(mg[cls] - dist, 0.0f);

    const float tot = rad + 0.5f * own_d2 + marg;

    // block reduce: alias s_red onto s_S (all s_S reads done after barrier)
    __syncthreads();
    float* s_red = &s_S[0][0];
    s_red[t] = tot;
    __syncthreads();
    for (int off = TB3 / 2; off > 0; off >>= 1) {
        if (t < off) s_red[t] += s_red[t + off];
        __syncthreads();
    }
    if (t == 0) atomicAdd(out, s_red[0] * (1.0f / (float)BATCH));
}

// ---------------------------------------------------------------------------
extern "C" void kernel_launch(void* const* d_in, const int* in_sizes, int n_in,
                              void* d_out, int out_size, void* d_ws, size_t ws_size,
                              hipStream_t stream) {
    const float* z       = (const float*)d_in[0];  // [BATCH, DIM] fp32
    const int*   y       = (const int*)d_in[1];    // [BATCH] int32
    const float* centers = (const float*)d_in[2];  // [NCLS, DIM] fp32
    // d_in[3] = initialized (all True, unused)
    const float* tr      = (const float*)d_in[4];  // [NCLS] target_radii
    const float* mg      = (const float*)d_in[5];  // [NCLS] margins
    float* out = (float*)d_out;

    float* ws        = (float*)d_ws;
    float* part_sums = ws;                                   // NB1*CD (5.24 MB)
    float* c2buf     = part_sums + (size_t)NB1 * CD;         // NCP
    float* gcnt      = c2buf + NCP;                          // NCLS
    short* cbf       = (short*)(gcnt + NCLS);                // NCP*DIM bf16

    hipMemsetAsync(gcnt, 0, NCLS * sizeof(float), stream);
    hipMemsetAsync(out, 0, sizeof(float), stream);

    k1_segsum<<<NB1, TB1, 0, stream>>>(z, y, part_sums, gcnt);
    k2_centers<<<NCP, 512, 0, stream>>>(part_sums, gcnt, centers, cbf, c2buf);
    k3_loss<<<NB3, TB3, 0, stream>>>(z, y, cbf, c2buf, tr, mg, out);
}

// Round 5
// 261.069 us; speedup vs baseline: 1.3785x; 1.0144x over previous
//
#include <hip/hip_runtime.h>
#include <math.h>

// Problem constants (from reference)
#define BATCH 262144
#define DIM   128
#define NCLS  40
#define NCP   48             // classes padded to 3 MFMA tiles of 16
#define CD    (NCLS * DIM)   // 5120
// LAMBDA_R=1.0, LAMBDA_C=0.5, LAMBDA_M=1.0, MOMENTUM=0.1

#define TB1 256            // k1: 4 waves/block
#define NB1 256            // k1 blocks: 1024 rows/block (5.24 MB partials)
#define TB3 256            // k3: 4 waves/block, 64 rows/wave
#define NB3 (BATCH / 256)  // 1024 blocks

typedef __attribute__((ext_vector_type(8))) short short8;  // 8 bf16 = 4 VGPRs
typedef __attribute__((ext_vector_type(4))) float f32x4;   // MFMA C/D

// fp32 -> bf16 round-to-nearest-even (bit trick; inputs are finite)
__device__ __forceinline__ short f2bf(float f) {
    unsigned u = __float_as_uint(f);
    u += 0x7fffu + ((u >> 16) & 1u);
    return (short)(u >> 16);
}

// 40-way static accumulator machinery: class index is wave-uniform per row
// (readlane), so a switch selects one of 40 NAMED float2 accumulators — no
// LDS RMW chain, no runtime-indexed array (rule #20: that goes to scratch).
#define K1_ALL(M) M(0) M(1) M(2) M(3) M(4) M(5) M(6) M(7) M(8) M(9) \
                  M(10) M(11) M(12) M(13) M(14) M(15) M(16) M(17) M(18) M(19) \
                  M(20) M(21) M(22) M(23) M(24) M(25) M(26) M(27) M(28) M(29) \
                  M(30) M(31) M(32) M(33) M(34) M(35) M(36) M(37) M(38) M(39)
#define K1_DECL(c) float2 a##c = {0.0f, 0.0f};
#define K1_CASE(c) case c: a##c.x += v.x; a##c.y += v.y; break;
#define K1_ST0(c)  s_buf[(c) * 64 + lane] = a##c;
#define K1_RMW(c)  { float2 t_ = s_buf[(c) * 64 + lane];                     \
                     t_.x += a##c.x; t_.y += a##c.y;                         \
                     s_buf[(c) * 64 + lane] = t_; }

// ---------------------------------------------------------------------------
// K1: segmented sum. Round-4 post-mortem: 82.6us = ~770 cyc/iter = naked HBM
// latency (8-deep ring covers ~240cyc; 82KB LDS -> 1 block/CU -> 2 waves/
// SIMD). Fixes: (a) float2 loads -- wave covers a full 128-dim row per
// instruction, halving iterations; (b) 16-deep prefetch ring (~480cyc in
// flight); (c) LDS 82->20.6KB: VGPR accumulators need LDS only at the end;
// one combine buffer, 4 barrier phases (wave0 stores, waves1-3 RMW-add;
// class addresses are compile-time constants so each phase pipelines).
// ~140 VGPR -> 3 blocks x 4 waves = 12 waves/CU (3/SIMD): 3x the latency
// hiding of round 4.
// ---------------------------------------------------------------------------
__global__ __launch_bounds__(TB1) void k1_segsum(const float* __restrict__ z,
                                                 const int* __restrict__ y,
                                                 float* __restrict__ ps,
                                                 float* __restrict__ gcnt) {
    __shared__ float2 s_buf[NCLS * 64];   // 20480 B (combine buffer)
    __shared__ float  s_cnt[NCLS];
    const int t = threadIdx.x;
    if (t < NCLS) s_cnt[t] = 0.0f;
    __syncthreads();

    const int w     = t >> 6;              // wave 0..3
    const int lane  = t & 63;
    const int rbase = blockIdx.x * 1024 + w * 256;   // 256 rows per wave

    // y values for my wave's 256 rows (4 named scalars, no arrays)
    const int yA = y[rbase + lane];
    const int yB = y[rbase + 64 + lane];
    const int yC = y[rbase + 128 + lane];
    const int yD = y[rbase + 192 + lane];
    atomicAdd(&s_cnt[yA], 1.0f);
    atomicAdd(&s_cnt[yB], 1.0f);
    atomicAdd(&s_cnt[yC], 1.0f);
    atomicAdd(&s_cnt[yD], 1.0f);

    // lane owns dims {2*lane, 2*lane+1}; one float2 per row
    const float* __restrict__ zp = z + (size_t)rbase * DIM + lane * 2;

    float2 vb[16];
#pragma unroll
    for (int q = 0; q < 16; ++q) vb[q] = *(const float2*)(zp + (size_t)q * DIM);

    K1_ALL(K1_DECL)                 // 40 float2 accumulators in VGPRs

#pragma unroll 1
    for (int jj = 0; jj < 4; ++jj) {
        int yj = yA;                 // cndmask chain, cheap, no array index
        if (jj == 1) yj = yB;
        if (jj == 2) yj = yC;
        if (jj == 3) yj = yD;
#pragma unroll 1
        for (int i0 = 0; i0 < 64; i0 += 16) {
#pragma unroll
            for (int q = 0; q < 16; ++q) {
                const int i = jj * 64 + i0 + q;     // row index in wave chunk
                const float2 v = vb[q];
                int sn = i + 16;
                if (sn > 255) sn = i;               // tail: dummy self-reload
                vb[q] = *(const float2*)(zp + (size_t)sn * DIM);
                const int cls = __builtin_amdgcn_readlane(yj, i0 + q);
                switch (cls) { K1_ALL(K1_CASE) default: break; }
            }
        }
    }

    // ---- combine 4 waves through one LDS buffer ----
    if (w == 0) { K1_ALL(K1_ST0) }
    __syncthreads();
    if (w == 1) { K1_ALL(K1_RMW) }
    __syncthreads();
    if (w == 2) { K1_ALL(K1_RMW) }
    __syncthreads();
    if (w == 3) { K1_ALL(K1_RMW) }
    __syncthreads();

    // write out: s_buf float2 index i covers floats {2i,2i+1} = ps layout
    float2* __restrict__ psb = (float2*)(ps + (size_t)blockIdx.x * CD);
    for (int i = t; i < NCLS * 64; i += TB1) psb[i] = s_buf[i];
    if (t < NCLS) atomicAdd(&gcnt[t], s_cnt[t]);
}

// ---------------------------------------------------------------------------
// K2: reduce partials -> EMA centers; emit bf16 c [48][128] + fp32 c2 [48].
// Round-2/4-proven: 512 threads/block, 4-way split of the 256-deep reduction.
// Pad classes 40..47: c=0, c2=1e30 (excluded from min; dot(z,0)=0).
// ---------------------------------------------------------------------------
__global__ __launch_bounds__(512) void k2_centers(const float* __restrict__ part_sums,
                                                  const float* __restrict__ gcnt,
                                                  const float* __restrict__ centers,
                                                  short* __restrict__ cbf,
                                                  float* __restrict__ c2_out) {
    const int j  = blockIdx.x;    // class (0..47)
    const int t  = threadIdx.x;
    const int d  = t & 127;       // dim
    const int qr = t >> 7;        // quarter 0..3

    if (j >= NCLS) {
        if (qr == 0) cbf[j * DIM + d] = 0;
        if (t == 0) c2_out[j] = 1e30f;
        return;                    // whole block exits before any barrier
    }

    const float* __restrict__ p = part_sums + j * DIM + d + (size_t)(qr * 64) * CD;
    float s = 0.0f;
#pragma unroll 8
    for (int b = 0; b < 64; ++b) s += p[(size_t)b * CD];

    __shared__ float red[512];
    red[t] = s;
    __syncthreads();

    float cv = 0.0f;
    if (qr == 0) {
        const float ssum = red[d] + red[d + 128] + red[d + 256] + red[d + 384];
        const float cnt  = gcnt[j];
        const float mean = ssum / fmaxf(cnt, 1.0f);
        const float ctr  = centers[j * DIM + d];
        const float ema  = 0.9f * ctr + 0.1f * mean;
        cv = (cnt > 0.0f) ? ema : ctr;
        cbf[j * DIM + d] = f2bf(cv);
    }
    __syncthreads();
    red[t] = cv * cv;    // qr!=0 contributes 0
    __syncthreads();
    for (int off = 256; off > 0; off >>= 1) {
        if (t < off) red[t] += red[t + off];
        __syncthreads();
    }
    if (t == 0) c2_out[j] = red[0];
}

// ---------------------------------------------------------------------------
// K3: MFMA Gram kernel. Per wave: 64 rows x 48 classes via 16x16x32 bf16
// MFMA (4 row-subtiles x 3 class-subtiles x 4 K-steps = 48 MFMA).
//  * z2 in unused col 48 of the stride-52 s_S rows; s_red aliased onto s_S.
//    LDS 53.2 KB permits 3 blocks/CU naturally; no min-waves pin.
//  * k4 fused: one global atomicAdd of the block partial (out pre-zeroed) —
//    round-2/4-proven.
// D layout: col=lane&15 (class), row=(lane>>4)*4+reg  [m89-verified].
// ---------------------------------------------------------------------------
__global__ __launch_bounds__(TB3) void k3_loss(const float* __restrict__ z,
                                               const int* __restrict__ y,
                                               const short* __restrict__ cbf,
                                               const float* __restrict__ c2,
                                               const float* __restrict__ tr,
                                               const float* __restrict__ mg,
                                               float* __restrict__ out) {
    __shared__ float s_S[4][64 * 52];   // 53248 B; col 48 of each row = z2
    __shared__ float s_c2[NCP];         // 192 B

    const int t = threadIdx.x;
    if (t < NCP) s_c2[t] = c2[t];

    const int w    = t >> 6;
    const int lane = t & 63;
    const int q    = lane >> 4;     // k-quad 0..3
    const int col  = lane & 15;
    const int wavebase = blockIdx.x * 256 + w * 64;

    // B fragments, preloaded once: 12 x short8 (48 VGPRs)
    short8 bfrag[3][4];
#pragma unroll
    for (int ct = 0; ct < 3; ++ct)
#pragma unroll
        for (int s = 0; s < 4; ++s)
            bfrag[ct][s] = *(const short8*)(cbf + (ct * 16 + col) * DIM + s * 32 + q * 8);

    __syncthreads();   // s_c2 visible to all waves

#pragma unroll 1
    for (int rt = 0; rt < 4; ++rt) {
        const float* __restrict__ zrow =
            z + (size_t)(wavebase + rt * 16 + col) * DIM + q * 8;

        float4 f[8];
#pragma unroll
        for (int s = 0; s < 4; ++s) {
            f[2 * s]     = *(const float4*)(zrow + s * 32);
            f[2 * s + 1] = *(const float4*)(zrow + s * 32 + 4);
        }

        // exact fp32 partial ||z||^2 over my 32 dims
        float zp = 0.0f;
#pragma unroll
        for (int i = 0; i < 8; ++i) {
            zp = fmaf(f[i].x, f[i].x, zp);
            zp = fmaf(f[i].y, f[i].y, zp);
            zp = fmaf(f[i].z, f[i].z, zp);
            zp = fmaf(f[i].w, f[i].w, zp);
        }

        // convert to bf16 A-fragments
        short8 afr[4];
#pragma unroll
        for (int s = 0; s < 4; ++s) {
            const float4 f0 = f[2 * s], f1 = f[2 * s + 1];
            afr[s][0] = f2bf(f0.x); afr[s][1] = f2bf(f0.y);
            afr[s][2] = f2bf(f0.z); afr[s][3] = f2bf(f0.w);
            afr[s][4] = f2bf(f1.x); afr[s][5] = f2bf(f1.y);
            afr[s][6] = f2bf(f1.z); afr[s][7] = f2bf(f1.w);
        }

        f32x4 acc0 = {0.f, 0.f, 0.f, 0.f};
        f32x4 acc1 = {0.f, 0.f, 0.f, 0.f};
        f32x4 acc2 = {0.f, 0.f, 0.f, 0.f};
#pragma unroll
        for (int s = 0; s < 4; ++s) {
            acc0 = __builtin_amdgcn_mfma_f32_16x16x32_bf16(afr[s], bfrag[0][s], acc0, 0, 0, 0);
            acc1 = __builtin_amdgcn_mfma_f32_16x16x32_bf16(afr[s], bfrag[1][s], acc1, 0, 0, 0);
            acc2 = __builtin_amdgcn_mfma_f32_16x16x32_bf16(afr[s], bfrag[2][s], acc2, 0, 0, 0);
        }

        // z2: reduce the 4 k-quads (lanes xor 16, 32); park in col 48
        zp += __shfl_xor(zp, 16);
        zp += __shfl_xor(zp, 32);
        if (q == 0) s_S[w][(rt * 16 + col) * 52 + 48] = zp;

        // dump S tile: row = rt*16 + q*4 + reg, class = ct*16 + col
#pragma unroll
        for (int reg = 0; reg < 4; ++reg) {
            const int rr = rt * 16 + q * 4 + reg;
            s_S[w][rr * 52 + col]      = acc0[reg];
            s_S[w][rr * 52 + 16 + col] = acc1[reg];
            s_S[w][rr * 52 + 32 + col] = acc2[reg];
        }
    }
    // s_S rows are per-wave private; in-order DS pipe makes them visible
    // to this wave without a barrier.

    // ---- scalar epilogue: 1 thread = 1 row ----
    const int row = blockIdx.x * 256 + t;
    const int cls = y[row];
    const float z2v = s_S[w][lane * 52 + 48];

    float own_d2 = 0.0f;
    float mind2  = 3.4e38f;
#pragma unroll
    for (int k = 0; k < 12; ++k) {
        const float4 Sv = *(const float4*)&s_S[w][lane * 52 + 4 * k];
        const float Se[4] = {Sv.x, Sv.y, Sv.z, Sv.w};
#pragma unroll
        for (int e = 0; e < 4; ++e) {
            const int j = 4 * k + e;
            float d2 = fmaxf(z2v + s_c2[j] - 2.0f * Se[e], 0.0f);
            const bool isown = (j == cls);
            own_d2 = isown ? d2 : own_d2;
            mind2  = isown ? mind2 : fminf(mind2, d2);
        }
    }

    const float r  = sqrtf(z2v);
    const float dd = r - tr[cls];
    const float ad = fabsf(dd);
    const float rad = (ad < 1.0f) ? 0.5f * dd * dd : ad - 0.5f;

    const float dist = sqrtf(mind2);
    const float marg = fmaxf(mg[cls] - dist, 0.0f);

    const float tot = rad + 0.5f * own_d2 + marg;

    // block reduce: alias s_red onto s_S (all s_S reads done after barrier)
    __syncthreads();
    float* s_red = &s_S[0][0];
    s_red[t] = tot;
    __syncthreads();
    for (int off = TB3 / 2; off > 0; off >>= 1) {
        if (t < off) s_red[t] += s_red[t + off];
        __syncthreads();
    }
    if (t == 0) atomicAdd(out, s_red[0] * (1.0f / (float)BATCH));
}

// ---------------------------------------------------------------------------
extern "C" void kernel_launch(void* const* d_in, const int* in_sizes, int n_in,
                              void* d_out, int out_size, void* d_ws, size_t ws_size,
                              hipStream_t stream) {
    const float* z       = (const float*)d_in[0];  // [BATCH, DIM] fp32
    const int*   y       = (const int*)d_in[1];    // [BATCH] int32
    const float* centers = (const float*)d_in[2];  // [NCLS, DIM] fp32
    // d_in[3] = initialized (all True, unused)
    const float* tr      = (const float*)d_in[4];  // [NCLS] target_radii
    const float* mg      = (const float*)d_in[5];  // [NCLS] margins
    float* out = (float*)d_out;

    float* ws        = (float*)d_ws;
    float* part_sums = ws;                                   // NB1*CD (5.24 MB)
    float* c2buf     = part_sums + (size_t)NB1 * CD;         // NCP
    float* gcnt      = c2buf + NCP;                          // NCLS
    short* cbf       = (short*)(gcnt + NCLS);                // NCP*DIM bf16

    hipMemsetAsync(gcnt, 0, NCLS * sizeof(float), stream);
    hipMemsetAsync(out, 0, sizeof(float), stream);

    k1_segsum<<<NB1, TB1, 0, stream>>>(z, y, part_sums, gcnt);
    k2_centers<<<NCP, 512, 0, stream>>>(part_sums, gcnt, centers, cbf, c2buf);
    k3_loss<<<NB3, TB3, 0, stream>>>(z, y, cbf, c2buf, tr, mg, out);
}